// Round 1
// baseline (183.211 us; speedup 1.0000x reference)
//
#include <hip/hip_runtime.h>

// Problem constants (fixed by the reference setup)
constexpr int NG = 2048;   // gaussians
constexpr int DF = 64;     // feature dim
constexpr int IW = 128;
constexpr int IH = 128;
#define P_NEAR 0.01f
#define P_BLUR 0.3f
#define P_AMIN (1.0f/255.0f)
#define P_AMAX 0.999f

// ---------------------------------------------------------------------------
// General 4x4 inverse (adjugate). Layout-agnostic: feeding row-major data to
// this (nominally column-major) code returns the row-major inverse.
__device__ inline void invert4x4(const float* m, float* inv) {
    inv[0]  =  m[5]*m[10]*m[15] - m[5]*m[11]*m[14] - m[9]*m[6]*m[15] + m[9]*m[7]*m[14] + m[13]*m[6]*m[11] - m[13]*m[7]*m[10];
    inv[4]  = -m[4]*m[10]*m[15] + m[4]*m[11]*m[14] + m[8]*m[6]*m[15] - m[8]*m[7]*m[14] - m[12]*m[6]*m[11] + m[12]*m[7]*m[10];
    inv[8]  =  m[4]*m[9]*m[15]  - m[4]*m[11]*m[13] - m[8]*m[5]*m[15] + m[8]*m[7]*m[13] + m[12]*m[5]*m[11] - m[12]*m[7]*m[9];
    inv[12] = -m[4]*m[9]*m[14]  + m[4]*m[10]*m[13] + m[8]*m[5]*m[14] - m[8]*m[6]*m[13] - m[12]*m[5]*m[10] + m[12]*m[6]*m[9];
    inv[1]  = -m[1]*m[10]*m[15] + m[1]*m[11]*m[14] + m[9]*m[2]*m[15] - m[9]*m[3]*m[14] - m[13]*m[2]*m[11] + m[13]*m[3]*m[10];
    inv[5]  =  m[0]*m[10]*m[15] - m[0]*m[11]*m[14] - m[8]*m[2]*m[15] + m[8]*m[3]*m[14] + m[12]*m[2]*m[11] - m[12]*m[3]*m[10];
    inv[9]  = -m[0]*m[9]*m[15]  + m[0]*m[11]*m[13] + m[8]*m[1]*m[15] - m[8]*m[3]*m[13] - m[12]*m[1]*m[11] + m[12]*m[3]*m[9];
    inv[13] =  m[0]*m[9]*m[14]  - m[0]*m[10]*m[13] - m[8]*m[1]*m[14] + m[8]*m[2]*m[13] + m[12]*m[1]*m[10] - m[12]*m[2]*m[9];
    inv[2]  =  m[1]*m[6]*m[15]  - m[1]*m[7]*m[14]  - m[5]*m[2]*m[15] + m[5]*m[3]*m[14] + m[13]*m[2]*m[7]  - m[13]*m[3]*m[6];
    inv[6]  = -m[0]*m[6]*m[15]  + m[0]*m[7]*m[14]  + m[4]*m[2]*m[15] - m[4]*m[3]*m[14] - m[12]*m[2]*m[7]  + m[12]*m[3]*m[6];
    inv[10] =  m[0]*m[5]*m[15]  - m[0]*m[7]*m[13]  - m[4]*m[1]*m[15] + m[4]*m[3]*m[13] + m[12]*m[1]*m[7]  - m[12]*m[3]*m[5];
    inv[14] = -m[0]*m[5]*m[14]  + m[0]*m[6]*m[13]  + m[4]*m[1]*m[14] - m[4]*m[2]*m[13] - m[12]*m[1]*m[6]  + m[12]*m[2]*m[5];
    inv[3]  = -m[1]*m[6]*m[11]  + m[1]*m[7]*m[10]  + m[5]*m[2]*m[11] - m[5]*m[3]*m[10] - m[9]*m[2]*m[7]   + m[9]*m[3]*m[6];
    inv[7]  =  m[0]*m[6]*m[11]  - m[0]*m[7]*m[10]  - m[4]*m[2]*m[11] + m[4]*m[3]*m[10] + m[8]*m[2]*m[7]   - m[8]*m[3]*m[6];
    inv[11] = -m[0]*m[5]*m[11]  + m[0]*m[7]*m[9]   + m[4]*m[1]*m[11] - m[4]*m[3]*m[9]  - m[8]*m[1]*m[7]   + m[8]*m[3]*m[5];
    inv[15] =  m[0]*m[5]*m[10]  - m[0]*m[6]*m[9]   - m[4]*m[1]*m[10] + m[4]*m[2]*m[9]  + m[8]*m[1]*m[6]   - m[8]*m[2]*m[5];
    float det = m[0]*inv[0] + m[1]*inv[4] + m[2]*inv[8] + m[3]*inv[12];
    det = 1.0f / det;
    #pragma unroll
    for (int i = 0; i < 16; ++i) inv[i] *= det;
}

// ---------------------------------------------------------------------------
// Kernel 1: per-gaussian projection. Writes z-keys + unsorted SoA params.
__global__ void preprocess_kernel(const float* __restrict__ means,
                                  const float* __restrict__ quats,
                                  const float* __restrict__ scales,
                                  const float* __restrict__ opac_logits,
                                  const float* __restrict__ c2o,
                                  const float* __restrict__ Kmat,
                                  float* __restrict__ zkey,
                                  float* __restrict__ up /* 6*NG SoA */) {
    int i = blockIdx.x * blockDim.x + threadIdx.x;
    if (i >= NG) return;

    float m[16];
    #pragma unroll
    for (int t = 0; t < 16; ++t) m[t] = c2o[t];
    float inv[16];
    invert4x4(m, inv);   // viewmat = inv(c2o), row-major

    const float fx = Kmat[0], fy = Kmat[4], cx = Kmat[2], cy = Kmat[5];

    float mx = means[i*3+0], my = means[i*3+1], mz = means[i*3+2];
    float X = inv[0]*mx + inv[1]*my + inv[2]*mz  + inv[3];
    float Y = inv[4]*mx + inv[5]*my + inv[6]*mz  + inv[7];
    float Z = inv[8]*mx + inv[9]*my + inv[10]*mz + inv[11];

    // quat -> rotation
    float qw = quats[i*4+0], qx = quats[i*4+1], qy = quats[i*4+2], qz = quats[i*4+3];
    float qn = rsqrtf(qw*qw + qx*qx + qy*qy + qz*qz);
    qw *= qn; qx *= qn; qy *= qn; qz *= qn;
    float R00 = 1.f - 2.f*(qy*qy + qz*qz), R01 = 2.f*(qx*qy - qw*qz), R02 = 2.f*(qx*qz + qw*qy);
    float R10 = 2.f*(qx*qy + qw*qz), R11 = 1.f - 2.f*(qx*qx + qz*qz), R12 = 2.f*(qy*qz - qw*qx);
    float R20 = 2.f*(qx*qz - qw*qy), R21 = 2.f*(qy*qz + qw*qx), R22 = 1.f - 2.f*(qx*qx + qy*qy);

    float s0 = expf(scales[i*3+0]), s1 = expf(scales[i*3+1]), s2 = expf(scales[i*3+2]);
    float M00 = R00*s0, M01 = R01*s1, M02 = R02*s2;
    float M10 = R10*s0, M11 = R11*s1, M12 = R12*s2;
    float M20 = R20*s0, M21 = R21*s1, M22 = R22*s2;

    // cov_w = M M^T (symmetric)
    float V[3][3];
    V[0][0] = M00*M00 + M01*M01 + M02*M02;
    V[0][1] = M00*M10 + M01*M11 + M02*M12;
    V[0][2] = M00*M20 + M01*M21 + M02*M22;
    V[1][1] = M10*M10 + M11*M11 + M12*M12;
    V[1][2] = M10*M20 + M11*M21 + M12*M22;
    V[2][2] = M20*M20 + M21*M21 + M22*M22;
    V[1][0] = V[0][1]; V[2][0] = V[0][2]; V[2][1] = V[1][2];

    // cov_c = Rv V Rv^T
    float Rv[3][3] = {{inv[0],inv[1],inv[2]},{inv[4],inv[5],inv[6]},{inv[8],inv[9],inv[10]}};
    float Tm[3][3], C[3][3];
    #pragma unroll
    for (int r = 0; r < 3; ++r)
        #pragma unroll
        for (int c = 0; c < 3; ++c)
            Tm[r][c] = Rv[r][0]*V[0][c] + Rv[r][1]*V[1][c] + Rv[r][2]*V[2][c];
    #pragma unroll
    for (int r = 0; r < 3; ++r)
        #pragma unroll
        for (int c = 0; c < 3; ++c)
            C[r][c] = Tm[r][0]*Rv[c][0] + Tm[r][1]*Rv[c][1] + Tm[r][2]*Rv[c][2];

    float rz = 1.0f / Z;
    float j00 = fx*rz, j02 = -fx*X*rz*rz;
    float j11 = fy*rz, j12 = -fy*Y*rz*rz;

    float c00 = j00*j00*C[0][0] + 2.f*j00*j02*C[0][2] + j02*j02*C[2][2];
    float c01 = j00*j11*C[0][1] + j00*j12*C[0][2] + j02*j11*C[1][2] + j02*j12*C[2][2];
    float c11 = j11*j11*C[1][1] + 2.f*j11*j12*C[1][2] + j12*j12*C[2][2];

    float a = c00 + P_BLUR;
    float b = c01;
    float c = c11 + P_BLUR;
    float det = a*c - b*b;

    float pmx = fx*X*rz + cx;
    float pmy = fy*Y*rz + cy;

    float lam = 0.5f*(a + c) + sqrtf(fmaxf(0.25f*(a - c)*(a - c) + b*b, 1e-12f));
    float radius = 3.0f * sqrtf(lam);
    bool valid = (Z > P_NEAR) && (det > 0.0f) && (radius > 3.0f);

    float op = 1.0f / (1.0f + expf(-opac_logits[i]));
    float cA, cB, cC;
    if (valid) {
        float rdet = 1.0f / det;
        cA = c * rdet; cB = -b * rdet; cC = a * rdet;
    } else {
        cA = 0.f; cB = 0.f; cC = 0.f; op = 0.f; pmx = 0.f; pmy = 0.f;
    }

    zkey[i] = Z;
    up[0*NG + i] = pmx;
    up[1*NG + i] = pmy;
    up[2*NG + i] = cA;
    up[3*NG + i] = cB;
    up[4*NG + i] = cC;
    up[5*NG + i] = op;
}

// ---------------------------------------------------------------------------
// Kernel 2: single-block bitonic argsort of z, stable via (z, idx) composite
// key (matches jnp.argsort's stable tie-breaking).
__global__ void sort_kernel(const float* __restrict__ zkey, int* __restrict__ sidx) {
    __shared__ float k[NG];
    __shared__ int   v[NG];
    const int tid = threadIdx.x;
    for (int i = tid; i < NG; i += 1024) { k[i] = zkey[i]; v[i] = i; }
    __syncthreads();
    for (int kk = 2; kk <= NG; kk <<= 1) {
        for (int j = kk >> 1; j > 0; j >>= 1) {
            for (int t = tid; t < NG; t += 1024) {
                int ixj = t ^ j;
                if (ixj > t) {
                    bool up_dir = ((t & kk) == 0);
                    float ka = k[t], kb = k[ixj];
                    int   va = v[t], vb = v[ixj];
                    bool a_gt_b = (ka > kb) || (ka == kb && va > vb);
                    bool do_swap = up_dir ? a_gt_b : !a_gt_b;
                    if (do_swap) { k[t] = kb; k[ixj] = ka; v[t] = vb; v[ixj] = va; }
                }
            }
            __syncthreads();
        }
    }
    for (int i = tid; i < NG; i += 1024) sidx[i] = v[i];
}

// ---------------------------------------------------------------------------
// Kernel 3: gather params into sorted AoS (8 floats/gaussian, float4-aligned).
__global__ void permute_kernel(const float* __restrict__ up,
                               const int* __restrict__ sidx,
                               float* __restrict__ sp) {
    int i = blockIdx.x * blockDim.x + threadIdx.x;
    if (i >= NG) return;
    int j = sidx[i];
    float4 p0 = make_float4(up[0*NG + j], up[1*NG + j], up[2*NG + j], up[3*NG + j]);
    float4 p1 = make_float4(up[4*NG + j], up[5*NG + j], __int_as_float(j), 0.0f);
    reinterpret_cast<float4*>(sp)[i*2 + 0] = p0;
    reinterpret_cast<float4*>(sp)[i*2 + 1] = p1;
}

// ---------------------------------------------------------------------------
// Kernel 4: render. One wave (64 lanes) per pixel. Per 64-gaussian chunk:
// lane i evaluates alpha for gaussian base+i, a shuffle-scan builds the
// transmittance prefix product, and a ballot-driven sparse loop accumulates
// only gaussians with alpha>0 (exact: zero-alpha gaussians contribute
// nothing in the reference either). Lane index doubles as feature index.
__global__ __launch_bounds__(256) void render_kernel(const float* __restrict__ sp,
                                                     const float* __restrict__ colors,
                                                     float* __restrict__ out) {
    const int lane = threadIdx.x & 63;
    const int wave = threadIdx.x >> 6;
    const int pid  = blockIdx.x * 4 + wave;          // pixel id, 0..16383
    const int h = pid >> 7;
    const int w = pid & 127;
    const float px = w + 0.5f;
    const float py = h + 0.5f;

    float acc = 0.0f;
    float T = 1.0f;

    for (int base = 0; base < NG; base += 64) {
        const float4* p = reinterpret_cast<const float4*>(sp + (size_t)(base + lane) * 8);
        float4 p0 = p[0];
        float4 p1 = p[1];
        float dx = px - p0.x;
        float dy = py - p0.y;
        float sigma = 0.5f * (p0.z * dx * dx + p1.x * dy * dy) + p0.w * dx * dy;
        float alpha = fminf(p1.y * __expf(-sigma), P_AMAX);
        if (!(sigma >= 0.0f && alpha >= P_AMIN)) alpha = 0.0f;

        // inclusive prefix product of (1 - alpha) across the wave
        float incl = 1.0f - alpha;
        #pragma unroll
        for (int off = 1; off < 64; off <<= 1) {
            float vv = __shfl_up(incl, off);
            if (lane >= off) incl *= vv;
        }
        float excl = __shfl_up(incl, 1);
        if (lane == 0) excl = 1.0f;
        float wgt = alpha * T * excl;     // this gaussian's compositing weight

        unsigned long long mask = __ballot(alpha > 0.0f);
        int oidx = __float_as_int(p1.z);  // original gaussian index (for colors)
        while (mask) {
            int j = __builtin_ctzll(mask);
            mask &= mask - 1;
            float wv = __shfl(wgt, j);
            int cj = __shfl(oidx, j);
            acc = fmaf(wv, colors[(size_t)cj * DF + lane], acc);
        }

        T *= __shfl(incl, 63);
        if (T < 1e-6f) break;   // residual contribution < ~3e-6, far below threshold
    }

    out[(size_t)pid * DF + lane] = acc;
}

// ---------------------------------------------------------------------------
extern "C" void kernel_launch(void* const* d_in, const int* in_sizes, int n_in,
                              void* d_out, int out_size, void* d_ws, size_t ws_size,
                              hipStream_t stream) {
    const float* means  = (const float*)d_in[0];
    const float* quats  = (const float*)d_in[1];
    const float* scales = (const float*)d_in[2];
    const float* opac   = (const float*)d_in[3];
    const float* colors = (const float*)d_in[4];
    const float* c2o    = (const float*)d_in[5];
    const float* Kmat   = (const float*)d_in[6];
    float* out = (float*)d_out;

    // workspace layout (floats): zkey[NG] | sidx[NG] | up[6*NG] | sp[8*NG]  = 128 KiB
    float* ws   = (float*)d_ws;
    float* zkey = ws;
    int*   sidx = (int*)(ws + NG);
    float* up   = ws + 2*NG;
    float* sp   = ws + 8*NG;

    preprocess_kernel<<<NG/256, 256, 0, stream>>>(means, quats, scales, opac, c2o, Kmat, zkey, up);
    sort_kernel<<<1, 1024, 0, stream>>>(zkey, sidx);
    permute_kernel<<<NG/256, 256, 0, stream>>>(up, sidx, sp);
    render_kernel<<<(IH*IW)/4, 256, 0, stream>>>(sp, colors, out);
}